// Round 1
// baseline (761.670 us; speedup 1.0000x reference)
//
#include <hip/hip_runtime.h>
#include <math.h>

#define BB   2
#define CINC 64
#define CAC  128
#define NN   1024
#define SSS  32

// ---- workspace layout (float offsets) ----
#define OFF_KT   0        // Wk2^T  [c(64)][i(128)]
#define OFF_VT   8192     // Wv2^T
#define OFF_QT   16384    // Wq2^T
#define OFF_WR   24576    // w_r [128]
#define OFF_WE21 24704    // We2@We1 [o(128)][c(64)]
#define WS_BASE_FLOATS 32896
#define OFF_F1T  32896    // Wf1^T [c(384)][o(128)]
#define OFF_F2T  82048    // Wf2^T [c(128)][o(128)]
#define WS_FULL_FLOATS 98432

// ---- shared memory layout (float offsets) ----
#define S_FTS 0        // [64][100]
#define S_ATT 6400     // [128][100]
#define S_H   19200    // [128][36]
#define S_A   23808    // [128][36]
#define S_Z0  28416    // [9][32]
#define S_Q   28704    // [128][4]
#define S_XYZ 29216    // [96]
#define S_WR  29312    // [128]
#define S_RED 29440    // [384]
#define SMEM_FLOATS 29824
#define SMEM_BYTES  (SMEM_FLOATS * 4)

// ---------- prep kernel 1: We21 = W_e2 @ W_e1 ----------
__global__ __launch_bounds__(256) void prep1(const float* __restrict__ We1,
                                             const float* __restrict__ We2,
                                             float* __restrict__ ws) {
    int e = blockIdx.x * 256 + threadIdx.x;   // 8192 entries, grid = 32
    int o = e >> 6, c = e & 63;
    float acc = 0.f;
    for (int m = 0; m < 128; ++m)
        acc = fmaf(We2[o * 128 + m], We1[m * 64 + c], acc);
    ws[OFF_WE21 + o * 64 + c] = acc;
}

// ---------- prep kernel 2: fused weights + transposes ----------
__global__ __launch_bounds__(256) void prep2(const float* __restrict__ Wq,
                                             const float* __restrict__ Wk,
                                             const float* __restrict__ Wv,
                                             const float* __restrict__ Wr1,
                                             const float* __restrict__ Wr2,
                                             const float* __restrict__ Wf1,
                                             const float* __restrict__ Wf2,
                                             float* __restrict__ ws, int use_t) {
    const float* we21 = ws + OFF_WE21;
    int e = blockIdx.x * 256 + threadIdx.x;
    if (e < 24576) {
        const float* W = (e < 8192) ? Wk : (e < 16384) ? Wv : Wq;
        float* dst = ws + ((e < 8192) ? OFF_KT : (e < 16384) ? OFF_VT : OFF_QT);
        int le = e & 8191;
        int i = le >> 6, c = le & 63;   // lanes: same i per 64-lane group (broadcast W), coalesced we21
        float acc = 0.f;
        for (int o = 0; o < 128; ++o)
            acc = fmaf(W[i * 128 + o], we21[o * 64 + c], acc);
        dst[c * 128 + i] = acc;
    } else if (e < 24704) {
        int i = e - 24576;
        float acc = 0.f;
        for (int m = 0; m < 64; ++m)
            acc = fmaf(Wr2[i * 64 + m], Wr1[m], acc);
        ws[OFF_WR + i] = acc;
    } else if (use_t) {
        if (e < 24704 + 49152) {
            int f = e - 24704;
            int c = f >> 7, o = f & 127;
            ws[OFF_F1T + f] = Wf1[o * 384 + c];
        } else if (e < 24704 + 49152 + 16384) {
            int f = e - (24704 + 49152);
            int c = f >> 7, o = f & 127;
            ws[OFF_F2T + c * 128 + o] = Wf2[o * 128 + c];
        }
    }
}

// ---------- main fused kernel: one block per (b, n) ----------
__global__ __launch_bounds__(256, 1) void fused_main(
        const float* __restrict__ gxyz, const float* __restrict__ gfts,
        const float* __restrict__ qxyz, const float* __restrict__ Wstd,
        const float* __restrict__ Wf1,  const float* __restrict__ bf1,
        const float* __restrict__ Wf2,  const float* __restrict__ bf2,
        const float* __restrict__ ws,   float* __restrict__ out, int use_t) {
    extern __shared__ float sm[];
    float* s_fts = sm + S_FTS;
    float* s_att = sm + S_ATT;
    float* s_h   = sm + S_H;
    float* s_a   = sm + S_A;
    float* s_z0  = sm + S_Z0;
    float* s_q   = sm + S_Q;
    float* s_xyz = sm + S_XYZ;
    float* s_wr  = sm + S_WR;
    float* s_red = sm + S_RED;

    const int t   = threadIdx.x;
    const int bid = blockIdx.x;
    const int b   = bid >> 10;
    const int n   = bid & 1023;

    // ---------- Phase A: stage fts tile + xyz_rel + w_r, zero reduction buf ----------
    {
        const float* gb = gfts + b * (CINC * 3 * NN * SSS) + n * SSS;
        // fts[c][m], m = d*32+s ; vectorized float4 over s
        for (int l4 = t; l4 < 1536; l4 += 256) {       // 6 iters
            int c  = l4 / 24;
            int m4 = (l4 - c * 24) * 4;                // 0,4,...,92
            int d  = m4 >> 5, s = m4 & 31;
            float4 v = *(const float4*)(gb + (c * 3 + d) * (NN * SSS) + s);
            *(float4*)(s_fts + c * 100 + m4) = v;
        }
        if (t < 96) {
            int d = t >> 5, s = t & 31;
            s_xyz[t] = gxyz[((b * NN + n) * SSS + s) * 3 + d] - qxyz[(b * NN + n) * 3 + d];
        }
        if (t < 128) s_wr[t] = ws[OFF_WR + t];
        s_red[t] = 0.f;
        if (t < 128) s_red[256 + t] = 0.f;
    }
    __syncthreads();

    // ---------- Phase A2: q[i][d] (s=0 column) ----------
    if (t < 128) {
        const float* qtw = ws + OFF_QT;
        float q0 = 0.f, q1 = 0.f, q2 = 0.f;
        for (int c = 0; c < 64; ++c) {
            float w = qtw[c * 128 + t];
            q0 = fmaf(w, s_fts[c * 100 + 0],  q0);
            q1 = fmaf(w, s_fts[c * 100 + 32], q1);
            q2 = fmaf(w, s_fts[c * 100 + 64], q2);
        }
        s_q[t * 4 + 0] = q0; s_q[t * 4 + 1] = q1; s_q[t * 4 + 2] = q2;
    }
    __syncthreads();

    // ---------- Phase B: k,v = Wk2/Wv2 @ fts  (per-thread 4i x 12m tile) ----------
    const int ib = (t >> 3) << 2;    // 0..124
    const int mb = (t & 7) * 12;     // 0..84
    float ka[4][12], va[4][12];
    #pragma unroll
    for (int r = 0; r < 4; ++r)
        #pragma unroll
        for (int j = 0; j < 12; ++j) { ka[r][j] = 0.f; va[r][j] = 0.f; }
    {
        const float* kt = ws + OFF_KT;
        const float* vt = ws + OFF_VT;
        for (int c = 0; c < 64; ++c) {
            float4 wk = *(const float4*)(kt + c * 128 + ib);
            float4 wv = *(const float4*)(vt + c * 128 + ib);
            const float* fp = s_fts + c * 100 + mb;
            float4 f0 = *(const float4*)(fp);
            float4 f1 = *(const float4*)(fp + 4);
            float4 f2 = *(const float4*)(fp + 8);
            float f[12]  = {f0.x, f0.y, f0.z, f0.w, f1.x, f1.y, f1.z, f1.w,
                            f2.x, f2.y, f2.z, f2.w};
            float wks[4] = {wk.x, wk.y, wk.z, wk.w};
            float wvs[4] = {wv.x, wv.y, wv.z, wv.w};
            #pragma unroll
            for (int r = 0; r < 4; ++r)
                #pragma unroll
                for (int j = 0; j < 12; ++j) {
                    ka[r][j] = fmaf(wks[r], f[j], ka[r][j]);
                    va[r][j] = fmaf(wvs[r], f[j], va[r][j]);
                }
        }
    }
    // Phase B-post: attn = q - k + pos ; v' = v + pos (v' stays in registers)
    #pragma unroll
    for (int r = 0; r < 4; ++r) {
        int i = ib + r;
        float wr = s_wr[i];
        #pragma unroll
        for (int j = 0; j < 12; ++j) {
            int m = mb + j;
            int d = m >> 5;
            float pos = wr * s_xyz[m];
            s_att[i * 100 + m] = s_q[i * 4 + d] - ka[r][j] + pos;
            va[r][j] += pos;
        }
    }
    __syncthreads();

    // ---------- Phase C: z0[j][kk][s] = sum_i Wstd[j][i] * attn[i][kk][s] ----------
    for (int o = t; o < 288; o += 256) {
        int j = o / 96;
        int rem = o - j * 96;           // kk*32 + s
        const float* wrow = Wstd + j * 128;
        float acc = 0.f;
        for (int i = 0; i < 128; ++i)
            acc = fmaf(wrow[i], s_att[i * 100 + rem], acc);
        s_z0[o] = acc;                  // layout (j*3+kk)*32+s
    }
    __syncthreads();

    // ---------- Phase D: attn2[i][kk][s] = sum_j attn[i][j][s]*z0[j][kk][s] (in place) ----------
    for (int e = t; e < 4096; e += 256) {
        int i = e >> 5, s = e & 31;
        float a0 = s_att[i * 100 + s];
        float a1 = s_att[i * 100 + 32 + s];
        float a2 = s_att[i * 100 + 64 + s];
        #pragma unroll
        for (int kk = 0; kk < 3; ++kk) {
            float z0v = s_z0[(0 * 3 + kk) * 32 + s];
            float z1v = s_z0[(1 * 3 + kk) * 32 + s];
            float z2v = s_z0[(2 * 3 + kk) * 32 + s];
            s_att[i * 100 + kk * 32 + s] = a0 * z0v + a1 * z1v + a2 * z2v;
        }
    }
    __syncthreads();

    // ---------- Phase E: h = relu(Wf1 @ attn2 + b_f1)  (4o x 4s tiles) ----------
    const int ob = (t >> 3) << 2;
    const int sb = (t & 7) << 2;
    {
        float hacc[4][4];
        #pragma unroll
        for (int r = 0; r < 4; ++r)
            #pragma unroll
            for (int x = 0; x < 4; ++x) hacc[r][x] = 0.f;
        if (use_t) {
            const float* f1t = ws + OFF_F1T;
            for (int i = 0; i < 128; ++i) {
                #pragma unroll
                for (int kk = 0; kk < 3; ++kk) {
                    float4 av4 = *(const float4*)(s_att + i * 100 + kk * 32 + sb);
                    float4 w4  = *(const float4*)(f1t + (i * 3 + kk) * 128 + ob);
                    float av[4] = {av4.x, av4.y, av4.z, av4.w};
                    float w[4]  = {w4.x, w4.y, w4.z, w4.w};
                    #pragma unroll
                    for (int r = 0; r < 4; ++r)
                        #pragma unroll
                        for (int x = 0; x < 4; ++x)
                            hacc[r][x] = fmaf(w[r], av[x], hacc[r][x]);
                }
            }
        } else {
            for (int i = 0; i < 128; ++i) {
                #pragma unroll
                for (int kk = 0; kk < 3; ++kk) {
                    float4 av4 = *(const float4*)(s_att + i * 100 + kk * 32 + sb);
                    float av[4] = {av4.x, av4.y, av4.z, av4.w};
                    int c = i * 3 + kk;
                    float w[4];
                    #pragma unroll
                    for (int r = 0; r < 4; ++r) w[r] = Wf1[(ob + r) * 384 + c];
                    #pragma unroll
                    for (int r = 0; r < 4; ++r)
                        #pragma unroll
                        for (int x = 0; x < 4; ++x)
                            hacc[r][x] = fmaf(w[r], av[x], hacc[r][x]);
                }
            }
        }
        #pragma unroll
        for (int r = 0; r < 4; ++r) {
            float bias = bf1[ob + r];
            float4 hv;
            hv.x = fmaxf(hacc[r][0] + bias, 0.f);
            hv.y = fmaxf(hacc[r][1] + bias, 0.f);
            hv.z = fmaxf(hacc[r][2] + bias, 0.f);
            hv.w = fmaxf(hacc[r][3] + bias, 0.f);
            *(float4*)(s_h + (ob + r) * 36 + sb) = hv;
        }
    }
    __syncthreads();

    // ---------- Phase F: logits a = Wf2 @ h + b_f2 ----------
    {
        float facc[4][4];
        #pragma unroll
        for (int r = 0; r < 4; ++r)
            #pragma unroll
            for (int x = 0; x < 4; ++x) facc[r][x] = 0.f;
        if (use_t) {
            const float* f2t = ws + OFF_F2T;
            for (int c = 0; c < 128; ++c) {
                float4 hv4 = *(const float4*)(s_h + c * 36 + sb);
                float4 w4  = *(const float4*)(f2t + c * 128 + ob);
                float hv[4] = {hv4.x, hv4.y, hv4.z, hv4.w};
                float w[4]  = {w4.x, w4.y, w4.z, w4.w};
                #pragma unroll
                for (int r = 0; r < 4; ++r)
                    #pragma unroll
                    for (int x = 0; x < 4; ++x)
                        facc[r][x] = fmaf(w[r], hv[x], facc[r][x]);
            }
        } else {
            for (int c = 0; c < 128; ++c) {
                float4 hv4 = *(const float4*)(s_h + c * 36 + sb);
                float hv[4] = {hv4.x, hv4.y, hv4.z, hv4.w};
                float w[4];
                #pragma unroll
                for (int r = 0; r < 4; ++r) w[r] = Wf2[(ob + r) * 128 + c];
                #pragma unroll
                for (int r = 0; r < 4; ++r)
                    #pragma unroll
                    for (int x = 0; x < 4; ++x)
                        facc[r][x] = fmaf(w[r], hv[x], facc[r][x]);
            }
        }
        #pragma unroll
        for (int r = 0; r < 4; ++r) {
            float bias = bf2[ob + r];
            float4 av;
            av.x = facc[r][0] + bias;
            av.y = facc[r][1] + bias;
            av.z = facc[r][2] + bias;
            av.w = facc[r][3] + bias;
            *(float4*)(s_a + (ob + r) * 36 + sb) = av;
        }
    }
    __syncthreads();

    // ---------- Phase G: softmax over s (scale 1/sqrt(128)) ----------
    if (t < 128) {
        float* row = s_a + t * 36;
        float mx = -INFINITY;
        #pragma unroll
        for (int s = 0; s < 32; ++s) mx = fmaxf(mx, row[s]);
        const float inv = 0.08838834764831845f;   // 1/sqrt(128)
        float ex[32];
        float sum = 0.f;
        #pragma unroll
        for (int s = 0; s < 32; ++s) { ex[s] = __expf((row[s] - mx) * inv); sum += ex[s]; }
        float rs = 1.f / sum;
        #pragma unroll
        for (int s = 0; s < 32; ++s) row[s] = ex[s] * rs;
    }
    __syncthreads();

    // ---------- Phase H: resi[i][d] = sum_s a[i][s] * v'[i][d][s] ----------
    #pragma unroll
    for (int r = 0; r < 4; ++r) {
        int i = ib + r;
        float pr[3] = {0.f, 0.f, 0.f};
        #pragma unroll
        for (int j = 0; j < 12; ++j) {
            int m = mb + j;
            int d = m >> 5, s = m & 31;
            pr[d] = fmaf(s_a[i * 36 + s], va[r][j], pr[d]);
        }
        #pragma unroll
        for (int d = 0; d < 3; ++d)
            if (pr[d] != 0.f) atomicAdd(&s_red[i * 3 + d], pr[d]);
    }
    __syncthreads();

    // write out: out[b][i][d][n], note i*3+d == e
    for (int e = t; e < 384; e += 256)
        out[(b * 384 + e) * NN + n] = s_red[e];
}

extern "C" void kernel_launch(void* const* d_in, const int* in_sizes, int n_in,
                              void* d_out, int out_size, void* d_ws, size_t ws_size,
                              hipStream_t stream) {
    const float* gxyz = (const float*)d_in[0];
    const float* gfts = (const float*)d_in[1];
    const float* qxyz = (const float*)d_in[2];
    const float* We1  = (const float*)d_in[3];
    const float* We2  = (const float*)d_in[4];
    const float* Wq   = (const float*)d_in[5];
    const float* Wk   = (const float*)d_in[6];
    const float* Wv   = (const float*)d_in[7];
    const float* Wr1  = (const float*)d_in[8];
    const float* Wr2  = (const float*)d_in[9];
    const float* Wstd = (const float*)d_in[10];
    const float* Wf1  = (const float*)d_in[11];
    const float* bf1  = (const float*)d_in[12];
    const float* Wf2  = (const float*)d_in[13];
    const float* bf2  = (const float*)d_in[14];
    float* out = (float*)d_out;
    float* ws  = (float*)d_ws;

    int use_t = (ws_size >= (size_t)WS_FULL_FLOATS * sizeof(float)) ? 1 : 0;

    // opt-in to >64KB dynamic LDS (idempotent; safe under graph capture)
    (void)hipFuncSetAttribute((const void*)fused_main,
                              hipFuncAttributeMaxDynamicSharedMemorySize, SMEM_BYTES);

    prep1<<<32, 256, 0, stream>>>(We1, We2, ws);
    prep2<<<use_t ? 353 : 97, 256, 0, stream>>>(Wq, Wk, Wv, Wr1, Wr2, Wf1, Wf2, ws, use_t);
    fused_main<<<BB * NN, 256, SMEM_BYTES, stream>>>(gxyz, gfts, qxyz, Wstd,
                                                     Wf1, bf1, Wf2, bf2, ws, out, use_t);
}

// Round 2
// 486.395 us; speedup vs baseline: 1.5659x; 1.5659x over previous
//
#include <hip/hip_runtime.h>
#include <math.h>

#define BB   2
#define CINC 64
#define CAC  128
#define NN   1024
#define SSS  32

// ---- workspace layout (float offsets) ----
#define OFF_KT   0        // Wk2^T  [c(64)][i(128)]
#define OFF_VT   8192     // Wv2^T
#define OFF_QT   16384    // Wq2^T
#define OFF_WR   24576    // w_r [128]
#define OFF_WE21 24704    // We2@We1 [o(128)][c(64)]
#define WS_BASE_FLOATS 32896
#define OFF_F1T  32896    // Wf1^T [c(384)][o(128)]
#define OFF_F2T  82048    // Wf2^T [c(128)][o(128)]
#define WS_FULL_FLOATS 98432

// ---- shared memory layout (float offsets) ----
// s_att [128][96] is dead after Phase E's reads -> s_h/s_a alias into it.
// s_fts [64][100] is dead after Phase B.
#define S_ATT 0        // [128][96]  (stride 96)
#define S_H   0        // alias: [128][36] (valid from post-E barrier)
#define S_A   4608     // alias: [128][36]
#define S_FTS 12288    // [64][100]
#define S_Z0  18688    // [9][32]
#define S_Q   18976    // [128][4]
#define S_XYZ 19488    // [96]
#define S_WR  19584    // [128]
#define S_RED 19712    // [384]
#define SMEM_FLOATS 20096
#define SMEM_BYTES  (SMEM_FLOATS * 4)   // 80384 B -> 2 blocks/CU (160 KiB LDS)

// ---------- prep kernel 1: We21 = W_e2 @ W_e1 ----------
__global__ __launch_bounds__(256) void prep1(const float* __restrict__ We1,
                                             const float* __restrict__ We2,
                                             float* __restrict__ ws) {
    int e = blockIdx.x * 256 + threadIdx.x;   // 8192 entries, grid = 32
    int o = e >> 6, c = e & 63;
    float acc = 0.f;
    for (int m = 0; m < 128; ++m)
        acc = fmaf(We2[o * 128 + m], We1[m * 64 + c], acc);
    ws[OFF_WE21 + o * 64 + c] = acc;
}

// ---------- prep kernel 2: fused weights + transposes ----------
__global__ __launch_bounds__(256) void prep2(const float* __restrict__ Wq,
                                             const float* __restrict__ Wk,
                                             const float* __restrict__ Wv,
                                             const float* __restrict__ Wr1,
                                             const float* __restrict__ Wr2,
                                             const float* __restrict__ Wf1,
                                             const float* __restrict__ Wf2,
                                             float* __restrict__ ws, int use_t) {
    const float* we21 = ws + OFF_WE21;
    int e = blockIdx.x * 256 + threadIdx.x;
    if (e < 24576) {
        const float* W = (e < 8192) ? Wk : (e < 16384) ? Wv : Wq;
        float* dst = ws + ((e < 8192) ? OFF_KT : (e < 16384) ? OFF_VT : OFF_QT);
        int le = e & 8191;
        int i = le >> 6, c = le & 63;
        float acc = 0.f;
        for (int o = 0; o < 128; ++o)
            acc = fmaf(W[i * 128 + o], we21[o * 64 + c], acc);
        dst[c * 128 + i] = acc;
    } else if (e < 24704) {
        int i = e - 24576;
        float acc = 0.f;
        for (int m = 0; m < 64; ++m)
            acc = fmaf(Wr2[i * 64 + m], Wr1[m], acc);
        ws[OFF_WR + i] = acc;
    } else if (use_t) {
        if (e < 24704 + 49152) {
            int f = e - 24704;
            int c = f >> 7, o = f & 127;
            ws[OFF_F1T + f] = Wf1[o * 384 + c];
        } else if (e < 24704 + 49152 + 16384) {
            int f = e - (24704 + 49152);
            int c = f >> 7, o = f & 127;
            ws[OFF_F2T + c * 128 + o] = Wf2[o * 128 + c];
        }
    }
}

// ---------- main fused kernel: one block per (b, n), 2 blocks/CU ----------
__global__ __launch_bounds__(256, 2) void fused_main(
        const float* __restrict__ gxyz, const float* __restrict__ gfts,
        const float* __restrict__ qxyz, const float* __restrict__ Wstd,
        const float* __restrict__ Wf1,  const float* __restrict__ bf1,
        const float* __restrict__ Wf2,  const float* __restrict__ bf2,
        const float* __restrict__ ws,   float* __restrict__ out, int use_t) {
    extern __shared__ float sm[];
    float* s_att = sm + S_ATT;
    float* s_h   = sm + S_H;     // alias of s_att[0:4608]
    float* s_a   = sm + S_A;     // alias of s_att[4608:9216]
    float* s_fts = sm + S_FTS;
    float* s_z0  = sm + S_Z0;
    float* s_q   = sm + S_Q;
    float* s_xyz = sm + S_XYZ;
    float* s_wr  = sm + S_WR;
    float* s_red = sm + S_RED;

    const int t   = threadIdx.x;
    const int bid = blockIdx.x;
    const int b   = bid >> 10;
    const int n   = bid & 1023;

    // ---------- Phase A: stage fts tile + xyz_rel + w_r ----------
    {
        const float* gb = gfts + b * (CINC * 3 * NN * SSS) + n * SSS;
        for (int l4 = t; l4 < 1536; l4 += 256) {       // 6 iters
            int c  = l4 / 24;
            int m4 = (l4 - c * 24) * 4;                // 0,4,...,92
            int d  = m4 >> 5, s = m4 & 31;
            float4 v = *(const float4*)(gb + (c * 3 + d) * (NN * SSS) + s);
            *(float4*)(s_fts + c * 100 + m4) = v;
        }
        if (t < 96) {
            int d = t >> 5, s = t & 31;
            s_xyz[t] = gxyz[((b * NN + n) * SSS + s) * 3 + d] - qxyz[(b * NN + n) * 3 + d];
        }
        if (t < 128) s_wr[t] = ws[OFF_WR + t];
    }
    __syncthreads();

    // ---------- Phase A2: q[i][d] (s=0 column) ----------
    if (t < 128) {
        const float* qtw = ws + OFF_QT;
        float q0 = 0.f, q1 = 0.f, q2 = 0.f;
        for (int c = 0; c < 64; ++c) {
            float w = qtw[c * 128 + t];
            q0 = fmaf(w, s_fts[c * 100 + 0],  q0);
            q1 = fmaf(w, s_fts[c * 100 + 32], q1);
            q2 = fmaf(w, s_fts[c * 100 + 64], q2);
        }
        s_q[t * 4 + 0] = q0; s_q[t * 4 + 1] = q1; s_q[t * 4 + 2] = q2;
    }
    __syncthreads();

    // ---------- Phase B: k,v = Wk2/Wv2 @ fts  (per-thread 4i x 12m tile) ----------
    const int ib = (t >> 3) << 2;    // 0..124
    const int mb = (t & 7) * 12;     // 0..84
    float ka[4][12], va[4][12];
    #pragma unroll
    for (int r = 0; r < 4; ++r)
        #pragma unroll
        for (int j = 0; j < 12; ++j) { ka[r][j] = 0.f; va[r][j] = 0.f; }
    {
        const float* kt = ws + OFF_KT;
        const float* vt = ws + OFF_VT;
        for (int c = 0; c < 64; ++c) {
            float4 wk = *(const float4*)(kt + c * 128 + ib);
            float4 wv = *(const float4*)(vt + c * 128 + ib);
            const float* fp = s_fts + c * 100 + mb;
            float4 f0 = *(const float4*)(fp);
            float4 f1 = *(const float4*)(fp + 4);
            float4 f2 = *(const float4*)(fp + 8);
            float f[12]  = {f0.x, f0.y, f0.z, f0.w, f1.x, f1.y, f1.z, f1.w,
                            f2.x, f2.y, f2.z, f2.w};
            float wks[4] = {wk.x, wk.y, wk.z, wk.w};
            float wvs[4] = {wv.x, wv.y, wv.z, wv.w};
            #pragma unroll
            for (int r = 0; r < 4; ++r)
                #pragma unroll
                for (int j = 0; j < 12; ++j) {
                    ka[r][j] = fmaf(wks[r], f[j], ka[r][j]);
                    va[r][j] = fmaf(wvs[r], f[j], va[r][j]);
                }
        }
    }
    // Phase B-post: attn = q - k + pos ; v' = v + pos (v' stays in registers)
    // write as float4 (stride 96: 8 mb-groups cover all 32 banks per b128 phase)
    #pragma unroll
    for (int r = 0; r < 4; ++r) {
        int i = ib + r;
        float wr = s_wr[i];
        float av[12];
        #pragma unroll
        for (int j = 0; j < 12; ++j) {
            int m = mb + j;
            int d = m >> 5;
            float pos = wr * s_xyz[m];
            av[j] = s_q[i * 4 + d] - ka[r][j] + pos;
            va[r][j] += pos;
        }
        float* ap = s_att + i * 96 + mb;
        *(float4*)(ap)     = make_float4(av[0], av[1], av[2],  av[3]);
        *(float4*)(ap + 4) = make_float4(av[4], av[5], av[6],  av[7]);
        *(float4*)(ap + 8) = make_float4(av[8], av[9], av[10], av[11]);
    }
    __syncthreads();

    // ---------- Phase C: z0[j][kk][s] = sum_i Wstd[j][i] * attn[i][kk][s] ----------
    for (int o = t; o < 288; o += 256) {
        int j = o / 96;
        int rem = o - j * 96;           // kk*32 + s
        const float* wrow = Wstd + j * 128;
        float acc = 0.f;
        for (int i = 0; i < 128; ++i)
            acc = fmaf(wrow[i], s_att[i * 96 + rem], acc);
        s_z0[o] = acc;                  // layout (j*3+kk)*32+s
    }
    __syncthreads();

    // ---------- Phase D: attn2[i][kk][s] = sum_j attn[i][j][s]*z0[j][kk][s] (in place) ----------
    for (int e = t; e < 4096; e += 256) {
        int i = e >> 5, s = e & 31;
        float a0 = s_att[i * 96 + s];
        float a1 = s_att[i * 96 + 32 + s];
        float a2 = s_att[i * 96 + 64 + s];
        #pragma unroll
        for (int kk = 0; kk < 3; ++kk) {
            float z0v = s_z0[(0 * 3 + kk) * 32 + s];
            float z1v = s_z0[(1 * 3 + kk) * 32 + s];
            float z2v = s_z0[(2 * 3 + kk) * 32 + s];
            s_att[i * 96 + kk * 32 + s] = a0 * z0v + a1 * z1v + a2 * z2v;
        }
    }
    __syncthreads();

    // ---------- Phase E: h = relu(Wf1 @ attn2 + b_f1)  (4o x 4s tiles) ----------
    const int ob = (t >> 3) << 2;
    const int sb = (t & 7) << 2;
    {
        float hacc[4][4];
        #pragma unroll
        for (int r = 0; r < 4; ++r)
            #pragma unroll
            for (int x = 0; x < 4; ++x) hacc[r][x] = 0.f;
        if (use_t) {
            const float* f1t = ws + OFF_F1T;
            for (int i = 0; i < 128; ++i) {
                #pragma unroll
                for (int kk = 0; kk < 3; ++kk) {
                    float4 av4 = *(const float4*)(s_att + i * 96 + kk * 32 + sb);
                    float4 w4  = *(const float4*)(f1t + (i * 3 + kk) * 128 + ob);
                    float av[4] = {av4.x, av4.y, av4.z, av4.w};
                    float w[4]  = {w4.x, w4.y, w4.z, w4.w};
                    #pragma unroll
                    for (int r = 0; r < 4; ++r)
                        #pragma unroll
                        for (int x = 0; x < 4; ++x)
                            hacc[r][x] = fmaf(w[r], av[x], hacc[r][x]);
                }
            }
        } else {
            for (int i = 0; i < 128; ++i) {
                #pragma unroll
                for (int kk = 0; kk < 3; ++kk) {
                    float4 av4 = *(const float4*)(s_att + i * 96 + kk * 32 + sb);
                    float av[4] = {av4.x, av4.y, av4.z, av4.w};
                    int c = i * 3 + kk;
                    float w[4];
                    #pragma unroll
                    for (int r = 0; r < 4; ++r) w[r] = Wf1[(ob + r) * 384 + c];
                    #pragma unroll
                    for (int r = 0; r < 4; ++r)
                        #pragma unroll
                        for (int x = 0; x < 4; ++x)
                            hacc[r][x] = fmaf(w[r], av[x], hacc[r][x]);
                }
            }
        }
        // s_att fully consumed; barrier, then write h into the aliased region
        __syncthreads();
        #pragma unroll
        for (int r = 0; r < 4; ++r) {
            float bias = bf1[ob + r];
            float4 hv;
            hv.x = fmaxf(hacc[r][0] + bias, 0.f);
            hv.y = fmaxf(hacc[r][1] + bias, 0.f);
            hv.z = fmaxf(hacc[r][2] + bias, 0.f);
            hv.w = fmaxf(hacc[r][3] + bias, 0.f);
            *(float4*)(s_h + (ob + r) * 36 + sb) = hv;
        }
    }
    __syncthreads();

    // ---------- Phase F: logits a = Wf2 @ h + b_f2 ----------
    {
        float facc[4][4];
        #pragma unroll
        for (int r = 0; r < 4; ++r)
            #pragma unroll
            for (int x = 0; x < 4; ++x) facc[r][x] = 0.f;
        if (use_t) {
            const float* f2t = ws + OFF_F2T;
            for (int c = 0; c < 128; ++c) {
                float4 hv4 = *(const float4*)(s_h + c * 36 + sb);
                float4 w4  = *(const float4*)(f2t + c * 128 + ob);
                float hv[4] = {hv4.x, hv4.y, hv4.z, hv4.w};
                float w[4]  = {w4.x, w4.y, w4.z, w4.w};
                #pragma unroll
                for (int r = 0; r < 4; ++r)
                    #pragma unroll
                    for (int x = 0; x < 4; ++x)
                        facc[r][x] = fmaf(w[r], hv[x], facc[r][x]);
            }
        } else {
            for (int c = 0; c < 128; ++c) {
                float4 hv4 = *(const float4*)(s_h + c * 36 + sb);
                float hv[4] = {hv4.x, hv4.y, hv4.z, hv4.w};
                float w[4];
                #pragma unroll
                for (int r = 0; r < 4; ++r) w[r] = Wf2[(ob + r) * 128 + c];
                #pragma unroll
                for (int r = 0; r < 4; ++r)
                    #pragma unroll
                    for (int x = 0; x < 4; ++x)
                        facc[r][x] = fmaf(w[r], hv[x], facc[r][x]);
            }
        }
        // writes go to s_a region (disjoint from s_h) -> no barrier needed first
        #pragma unroll
        for (int r = 0; r < 4; ++r) {
            float bias = bf2[ob + r];
            float4 av;
            av.x = facc[r][0] + bias;
            av.y = facc[r][1] + bias;
            av.z = facc[r][2] + bias;
            av.w = facc[r][3] + bias;
            *(float4*)(s_a + (ob + r) * 36 + sb) = av;
        }
    }
    __syncthreads();

    // ---------- Phase G: softmax over s (scale 1/sqrt(128)) ----------
    if (t < 128) {
        float* row = s_a + t * 36;
        float mx = -INFINITY;
        #pragma unroll
        for (int s = 0; s < 32; ++s) mx = fmaxf(mx, row[s]);
        const float inv = 0.08838834764831845f;   // 1/sqrt(128)
        float ex[32];
        float sum = 0.f;
        #pragma unroll
        for (int s = 0; s < 32; ++s) { ex[s] = __expf((row[s] - mx) * inv); sum += ex[s]; }
        float rs = 1.f / sum;
        #pragma unroll
        for (int s = 0; s < 32; ++s) row[s] = ex[s] * rs;
    }
    __syncthreads();

    // ---------- Phase H: resi[i][d] = sum_s a[i][s] * v'[i][d][s] ----------
    // 8 lanes (t&7 = 0..7, same wave) hold the s-partials for each i -> butterfly
    #pragma unroll
    for (int r = 0; r < 4; ++r) {
        int i = ib + r;
        float pr[3] = {0.f, 0.f, 0.f};
        #pragma unroll
        for (int j = 0; j < 12; ++j) {
            int m = mb + j;
            int d = m >> 5, s = m & 31;
            pr[d] = fmaf(s_a[i * 36 + s], va[r][j], pr[d]);
        }
        #pragma unroll
        for (int d = 0; d < 3; ++d) {
            float v = pr[d];
            v += __shfl_xor(v, 1);
            v += __shfl_xor(v, 2);
            v += __shfl_xor(v, 4);
            if ((t & 7) == 0) s_red[i * 3 + d] = v;
        }
    }
    __syncthreads();

    // write out: out[b][i][d][n], note i*3+d == e
    for (int e = t; e < 384; e += 256)
        out[(b * 384 + e) * NN + n] = s_red[e];
}

extern "C" void kernel_launch(void* const* d_in, const int* in_sizes, int n_in,
                              void* d_out, int out_size, void* d_ws, size_t ws_size,
                              hipStream_t stream) {
    const float* gxyz = (const float*)d_in[0];
    const float* gfts = (const float*)d_in[1];
    const float* qxyz = (const float*)d_in[2];
    const float* We1  = (const float*)d_in[3];
    const float* We2  = (const float*)d_in[4];
    const float* Wq   = (const float*)d_in[5];
    const float* Wk   = (const float*)d_in[6];
    const float* Wv   = (const float*)d_in[7];
    const float* Wr1  = (const float*)d_in[8];
    const float* Wr2  = (const float*)d_in[9];
    const float* Wstd = (const float*)d_in[10];
    const float* Wf1  = (const float*)d_in[11];
    const float* bf1  = (const float*)d_in[12];
    const float* Wf2  = (const float*)d_in[13];
    const float* bf2  = (const float*)d_in[14];
    float* out = (float*)d_out;
    float* ws  = (float*)d_ws;

    int use_t = (ws_size >= (size_t)WS_FULL_FLOATS * sizeof(float)) ? 1 : 0;

    (void)hipFuncSetAttribute((const void*)fused_main,
                              hipFuncAttributeMaxDynamicSharedMemorySize, SMEM_BYTES);

    prep1<<<32, 256, 0, stream>>>(We1, We2, ws);
    prep2<<<use_t ? 353 : 97, 256, 0, stream>>>(Wq, Wk, Wv, Wr1, Wr2, Wf1, Wf2, ws, use_t);
    fused_main<<<BB * NN, 256, SMEM_BYTES, stream>>>(gxyz, gfts, qxyz, Wstd,
                                                     Wf1, bf1, Wf2, bf2, ws, out, use_t);
}

// Round 3
// 408.112 us; speedup vs baseline: 1.8663x; 1.1918x over previous
//
#include <hip/hip_runtime.h>
#include <math.h>

#define BB   2
#define CINC 64
#define CAC  128
#define NN   1024
#define SSS  32

// ---- workspace layout (float offsets) ----
#define OFF_KT   0        // Wk2^T  [c(64)][i(128)]
#define OFF_VT   8192     // Wv2^T
#define OFF_QT   16384    // Wq2^T
#define OFF_WR   24576    // w_r [128]
#define OFF_WE21 24704    // We2@We1 [o(128)][c(64)]
#define WS_BASE_FLOATS 32896
#define OFF_F1T  32896    // Wf1^T [c(384)][o(128)]
#define OFF_F2T  82048    // Wf2^T [c(128)][o(128)]
#define WS_FULL_FLOATS 98432

// ---- shared memory layout (float offsets) ----
// s_att [128][96]; s_h/s_a alias into it (dead after Phase E reads).
// s_scr holds z0 (288, phases C/D) then red (384, phase H) — disjoint lifetimes.
#define S_ATT 0        // [128][96]
#define S_H   0        // alias: [128][36]
#define S_A   4608     // alias: [128][36]
#define S_SCR 12288    // 384: z0 then red
#define S_Q   12672    // [128][3]
#define S_XYZ 13056    // [96]
#define S_FT0 13152    // [192] fts at s=0, layout [c*3+d]
#define SMEM_FLOATS 13344
#define SMEM_BYTES  (SMEM_FLOATS * 4)   // 53376 B -> 3 blocks/CU

// ---------- prep kernel 1: We21 = W_e2 @ W_e1 ----------
__global__ __launch_bounds__(256) void prep1(const float* __restrict__ We1,
                                             const float* __restrict__ We2,
                                             float* __restrict__ ws) {
    int e = blockIdx.x * 256 + threadIdx.x;   // 8192 entries, grid = 32
    int o = e >> 6, c = e & 63;
    float acc = 0.f;
    for (int m = 0; m < 128; ++m)
        acc = fmaf(We2[o * 128 + m], We1[m * 64 + c], acc);
    ws[OFF_WE21 + o * 64 + c] = acc;
}

// ---------- prep kernel 2: fused weights + transposes ----------
__global__ __launch_bounds__(256) void prep2(const float* __restrict__ Wq,
                                             const float* __restrict__ Wk,
                                             const float* __restrict__ Wv,
                                             const float* __restrict__ Wr1,
                                             const float* __restrict__ Wr2,
                                             const float* __restrict__ Wf1,
                                             const float* __restrict__ Wf2,
                                             float* __restrict__ ws, int use_t) {
    const float* we21 = ws + OFF_WE21;
    int e = blockIdx.x * 256 + threadIdx.x;
    if (e < 24576) {
        const float* W = (e < 8192) ? Wk : (e < 16384) ? Wv : Wq;
        float* dst = ws + ((e < 8192) ? OFF_KT : (e < 16384) ? OFF_VT : OFF_QT);
        int le = e & 8191;
        int i = le >> 6, c = le & 63;
        float acc = 0.f;
        for (int o = 0; o < 128; ++o)
            acc = fmaf(W[i * 128 + o], we21[o * 64 + c], acc);
        dst[c * 128 + i] = acc;
    } else if (e < 24704) {
        int i = e - 24576;
        float acc = 0.f;
        for (int m = 0; m < 64; ++m)
            acc = fmaf(Wr2[i * 64 + m], Wr1[m], acc);
        ws[OFF_WR + i] = acc;
    } else if (use_t) {
        if (e < 24704 + 49152) {
            int f = e - 24704;
            int c = f >> 7, o = f & 127;
            ws[OFF_F1T + f] = Wf1[o * 384 + c];
        } else if (e < 24704 + 49152 + 16384) {
            int f = e - (24704 + 49152);
            int c = f >> 7, o = f & 127;
            ws[OFF_F2T + c * 128 + o] = Wf2[o * 128 + c];
        }
    }
}

// ---------- main fused kernel: one block per (b, n), 3 blocks/CU ----------
__global__ __launch_bounds__(256, 3) void fused_main(
        const float* __restrict__ gxyz, const float* __restrict__ gfts,
        const float* __restrict__ qxyz, const float* __restrict__ Wstd,
        const float* __restrict__ Wf1,  const float* __restrict__ bf1,
        const float* __restrict__ Wf2,  const float* __restrict__ bf2,
        const float* __restrict__ ws,   float* __restrict__ out, int use_t) {
    extern __shared__ float sm[];
    float* s_att = sm + S_ATT;
    float* s_h   = sm + S_H;     // alias of s_att[0:4608]
    float* s_a   = sm + S_A;     // alias of s_att[4608:9216]
    float* s_scr = sm + S_SCR;   // z0 (C/D) then red (H)
    float* s_q   = sm + S_Q;
    float* s_xyz = sm + S_XYZ;
    float* s_ft0 = sm + S_FT0;

    const int t   = threadIdx.x;
    const int bid = blockIdx.x;
    const int b   = bid >> 10;
    const int n   = bid & 1023;

    const float* gb = gfts + (size_t)b * (CINC * 3 * NN * SSS) + n * SSS;

    // ---------- Phase A: stage fts s=0 columns + xyz_rel ----------
    if (t < 192) s_ft0[t] = gb[(size_t)t * (NN * SSS)];   // [c*3+d] at s=0
    if (t >= 160) {
        int id = t - 160;                // 0..95
        int d = id >> 5, s = id & 31;
        s_xyz[id] = gxyz[((b * NN + n) * SSS + s) * 3 + d] - qxyz[(b * NN + n) * 3 + d];
    }
    __syncthreads();

    // ---------- Phase A2: q[i][d] from s=0 columns ----------
    if (t < 128) {
        const float* qtw = ws + OFF_QT;
        float q0 = 0.f, q1 = 0.f, q2 = 0.f;
        for (int c = 0; c < 64; ++c) {
            float w = qtw[c * 128 + t];
            q0 = fmaf(w, s_ft0[c * 3 + 0], q0);
            q1 = fmaf(w, s_ft0[c * 3 + 1], q1);
            q2 = fmaf(w, s_ft0[c * 3 + 2], q2);
        }
        s_q[t * 3 + 0] = q0; s_q[t * 3 + 1] = q1; s_q[t * 3 + 2] = q2;
    }
    __syncthreads();

    // ---------- Phase B: k,v = Wk2/Wv2 @ fts, fts direct from global ----------
    const int ib = (t >> 3) << 2;    // 0..124
    const int mb = (t & 7) * 12;     // 0..84
    // per-thread fts offsets: each float4 at m4 = mb+4q lies within one d
    int offm[3];
    #pragma unroll
    for (int q = 0; q < 3; ++q) {
        int m4 = mb + 4 * q;
        offm[q] = (m4 >> 5) * (NN * SSS) + (m4 & 31);
    }
    float ka[4][12], va[4][12];
    #pragma unroll
    for (int r = 0; r < 4; ++r)
        #pragma unroll
        for (int j = 0; j < 12; ++j) { ka[r][j] = 0.f; va[r][j] = 0.f; }
    {
        const float* kt = ws + OFF_KT;
        const float* vt = ws + OFF_VT;
        #pragma unroll 2
        for (int c = 0; c < 64; ++c) {
            const float* fb = gb + c * (3 * NN * SSS);
            float4 f0 = *(const float4*)(fb + offm[0]);
            float4 f1 = *(const float4*)(fb + offm[1]);
            float4 f2 = *(const float4*)(fb + offm[2]);
            float4 wk = *(const float4*)(kt + c * 128 + ib);
            float4 wv = *(const float4*)(vt + c * 128 + ib);
            float f[12]  = {f0.x, f0.y, f0.z, f0.w, f1.x, f1.y, f1.z, f1.w,
                            f2.x, f2.y, f2.z, f2.w};
            float wks[4] = {wk.x, wk.y, wk.z, wk.w};
            float wvs[4] = {wv.x, wv.y, wv.z, wv.w};
            #pragma unroll
            for (int r = 0; r < 4; ++r)
                #pragma unroll
                for (int j = 0; j < 12; ++j) {
                    ka[r][j] = fmaf(wks[r], f[j], ka[r][j]);
                    va[r][j] = fmaf(wvs[r], f[j], va[r][j]);
                }
        }
    }
    // Phase B-post: attn = q - k + pos ; v' = v + pos (v' stays in registers)
    {
        float4 wr4 = *(const float4*)(ws + OFF_WR + ib);
        float wrs[4] = {wr4.x, wr4.y, wr4.z, wr4.w};
        #pragma unroll
        for (int r = 0; r < 4; ++r) {
            int i = ib + r;
            float qv[3] = {s_q[i * 3 + 0], s_q[i * 3 + 1], s_q[i * 3 + 2]};
            float av[12];
            #pragma unroll
            for (int j = 0; j < 12; ++j) {
                int m = mb + j;
                int d = m >> 5;
                float pos = wrs[r] * s_xyz[m];
                av[j] = qv[d] - ka[r][j] + pos;
                va[r][j] += pos;
            }
            float* ap = s_att + i * 96 + mb;
            *(float4*)(ap)     = make_float4(av[0], av[1], av[2],  av[3]);
            *(float4*)(ap + 4) = make_float4(av[4], av[5], av[6],  av[7]);
            *(float4*)(ap + 8) = make_float4(av[8], av[9], av[10], av[11]);
        }
    }
    __syncthreads();

    // ---------- Phase C: z0[j][kk][s] = sum_i Wstd[j][i] * attn[i][kk][s] ----------
    for (int o = t; o < 288; o += 256) {
        int j = o / 96;
        int rem = o - j * 96;           // kk*32 + s
        const float* wrow = Wstd + j * 128;
        float acc = 0.f;
        for (int i = 0; i < 128; ++i)
            acc = fmaf(wrow[i], s_att[i * 96 + rem], acc);
        s_scr[o] = acc;                 // z0: layout (j*3+kk)*32+s
    }
    __syncthreads();

    // ---------- Phase D: attn2[i][kk][s] = sum_j attn[i][j][s]*z0[j][kk][s] ----------
    for (int e = t; e < 4096; e += 256) {
        int i = e >> 5, s = e & 31;
        float a0 = s_att[i * 96 + s];
        float a1 = s_att[i * 96 + 32 + s];
        float a2 = s_att[i * 96 + 64 + s];
        #pragma unroll
        for (int kk = 0; kk < 3; ++kk) {
            float z0v = s_scr[(0 * 3 + kk) * 32 + s];
            float z1v = s_scr[(1 * 3 + kk) * 32 + s];
            float z2v = s_scr[(2 * 3 + kk) * 32 + s];
            s_att[i * 96 + kk * 32 + s] = a0 * z0v + a1 * z1v + a2 * z2v;
        }
    }
    __syncthreads();

    // ---------- Phase E: h = relu(Wf1 @ attn2 + b_f1)  (4o x 4s tiles) ----------
    const int ob = (t >> 3) << 2;
    const int sb = (t & 7) << 2;
    {
        float hacc[4][4];
        #pragma unroll
        for (int r = 0; r < 4; ++r)
            #pragma unroll
            for (int x = 0; x < 4; ++x) hacc[r][x] = 0.f;
        if (use_t) {
            const float* f1t = ws + OFF_F1T;
            for (int i = 0; i < 128; ++i) {
                #pragma unroll
                for (int kk = 0; kk < 3; ++kk) {
                    float4 av4 = *(const float4*)(s_att + i * 96 + kk * 32 + sb);
                    float4 w4  = *(const float4*)(f1t + (i * 3 + kk) * 128 + ob);
                    float av[4] = {av4.x, av4.y, av4.z, av4.w};
                    float w[4]  = {w4.x, w4.y, w4.z, w4.w};
                    #pragma unroll
                    for (int r = 0; r < 4; ++r)
                        #pragma unroll
                        for (int x = 0; x < 4; ++x)
                            hacc[r][x] = fmaf(w[r], av[x], hacc[r][x]);
                }
            }
        } else {
            for (int i = 0; i < 128; ++i) {
                #pragma unroll
                for (int kk = 0; kk < 3; ++kk) {
                    float4 av4 = *(const float4*)(s_att + i * 96 + kk * 32 + sb);
                    float av[4] = {av4.x, av4.y, av4.z, av4.w};
                    int c = i * 3 + kk;
                    float w[4];
                    #pragma unroll
                    for (int r = 0; r < 4; ++r) w[r] = Wf1[(ob + r) * 384 + c];
                    #pragma unroll
                    for (int r = 0; r < 4; ++r)
                        #pragma unroll
                        for (int x = 0; x < 4; ++x)
                            hacc[r][x] = fmaf(w[r], av[x], hacc[r][x]);
                }
            }
        }
        // s_att fully consumed; barrier, then write h into the aliased region
        __syncthreads();
        #pragma unroll
        for (int r = 0; r < 4; ++r) {
            float bias = bf1[ob + r];
            float4 hv;
            hv.x = fmaxf(hacc[r][0] + bias, 0.f);
            hv.y = fmaxf(hacc[r][1] + bias, 0.f);
            hv.z = fmaxf(hacc[r][2] + bias, 0.f);
            hv.w = fmaxf(hacc[r][3] + bias, 0.f);
            *(float4*)(s_h + (ob + r) * 36 + sb) = hv;
        }
    }
    __syncthreads();

    // ---------- Phase F: logits a = Wf2 @ h + b_f2 ----------
    {
        float facc[4][4];
        #pragma unroll
        for (int r = 0; r < 4; ++r)
            #pragma unroll
            for (int x = 0; x < 4; ++x) facc[r][x] = 0.f;
        if (use_t) {
            const float* f2t = ws + OFF_F2T;
            for (int c = 0; c < 128; ++c) {
                float4 hv4 = *(const float4*)(s_h + c * 36 + sb);
                float4 w4  = *(const float4*)(f2t + c * 128 + ob);
                float hv[4] = {hv4.x, hv4.y, hv4.z, hv4.w};
                float w[4]  = {w4.x, w4.y, w4.z, w4.w};
                #pragma unroll
                for (int r = 0; r < 4; ++r)
                    #pragma unroll
                    for (int x = 0; x < 4; ++x)
                        facc[r][x] = fmaf(w[r], hv[x], facc[r][x]);
            }
        } else {
            for (int c = 0; c < 128; ++c) {
                float4 hv4 = *(const float4*)(s_h + c * 36 + sb);
                float hv[4] = {hv4.x, hv4.y, hv4.z, hv4.w};
                float w[4];
                #pragma unroll
                for (int r = 0; r < 4; ++r) w[r] = Wf2[(ob + r) * 128 + c];
                #pragma unroll
                for (int r = 0; r < 4; ++r)
                    #pragma unroll
                    for (int x = 0; x < 4; ++x)
                        facc[r][x] = fmaf(w[r], hv[x], facc[r][x]);
            }
        }
        #pragma unroll
        for (int r = 0; r < 4; ++r) {
            float bias = bf2[ob + r];
            float4 av;
            av.x = facc[r][0] + bias;
            av.y = facc[r][1] + bias;
            av.z = facc[r][2] + bias;
            av.w = facc[r][3] + bias;
            *(float4*)(s_a + (ob + r) * 36 + sb) = av;
        }
    }
    __syncthreads();

    // ---------- Phase G: softmax over s (scale 1/sqrt(128)) ----------
    if (t < 128) {
        float* row = s_a + t * 36;
        float mx = -INFINITY;
        #pragma unroll
        for (int s = 0; s < 32; ++s) mx = fmaxf(mx, row[s]);
        const float inv = 0.08838834764831845f;   // 1/sqrt(128)
        float ex[32];
        float sum = 0.f;
        #pragma unroll
        for (int s = 0; s < 32; ++s) { ex[s] = __expf((row[s] - mx) * inv); sum += ex[s]; }
        float rs = 1.f / sum;
        #pragma unroll
        for (int s = 0; s < 32; ++s) row[s] = ex[s] * rs;
    }
    __syncthreads();

    // ---------- Phase H: resi[i][d] = sum_s a[i][s] * v'[i][d][s] ----------
    #pragma unroll
    for (int r = 0; r < 4; ++r) {
        int i = ib + r;
        float pr[3] = {0.f, 0.f, 0.f};
        #pragma unroll
        for (int q = 0; q < 3; ++q) {
            int m4 = mb + 4 * q;
            int d = m4 >> 5, s4 = m4 & 31;
            float4 a4 = *(const float4*)(s_a + i * 36 + s4);
            pr[d] = fmaf(a4.x, va[r][4 * q + 0], pr[d]);
            pr[d] = fmaf(a4.y, va[r][4 * q + 1], pr[d]);
            pr[d] = fmaf(a4.z, va[r][4 * q + 2], pr[d]);
            pr[d] = fmaf(a4.w, va[r][4 * q + 3], pr[d]);
        }
        #pragma unroll
        for (int d = 0; d < 3; ++d) {
            float v = pr[d];
            v += __shfl_xor(v, 1);
            v += __shfl_xor(v, 2);
            v += __shfl_xor(v, 4);
            if ((t & 7) == 0) s_scr[i * 3 + d] = v;
        }
    }
    __syncthreads();

    // write out: out[b][i][d][n], note i*3+d == e
    for (int e = t; e < 384; e += 256)
        out[(b * 384 + e) * NN + n] = s_scr[e];
}

extern "C" void kernel_launch(void* const* d_in, const int* in_sizes, int n_in,
                              void* d_out, int out_size, void* d_ws, size_t ws_size,
                              hipStream_t stream) {
    const float* gxyz = (const float*)d_in[0];
    const float* gfts = (const float*)d_in[1];
    const float* qxyz = (const float*)d_in[2];
    const float* We1  = (const float*)d_in[3];
    const float* We2  = (const float*)d_in[4];
    const float* Wq   = (const float*)d_in[5];
    const float* Wk   = (const float*)d_in[6];
    const float* Wv   = (const float*)d_in[7];
    const float* Wr1  = (const float*)d_in[8];
    const float* Wr2  = (const float*)d_in[9];
    const float* Wstd = (const float*)d_in[10];
    const float* Wf1  = (const float*)d_in[11];
    const float* bf1  = (const float*)d_in[12];
    const float* Wf2  = (const float*)d_in[13];
    const float* bf2  = (const float*)d_in[14];
    float* out = (float*)d_out;
    float* ws  = (float*)d_ws;

    int use_t = (ws_size >= (size_t)WS_FULL_FLOATS * sizeof(float)) ? 1 : 0;

    (void)hipFuncSetAttribute((const void*)fused_main,
                              hipFuncAttributeMaxDynamicSharedMemorySize, SMEM_BYTES);

    prep1<<<32, 256, 0, stream>>>(We1, We2, ws);
    prep2<<<use_t ? 353 : 97, 256, 0, stream>>>(Wq, Wk, Wv, Wr1, Wr2, Wf1, Wf2, ws, use_t);
    fused_main<<<BB * NN, 256, SMEM_BYTES, stream>>>(gxyz, gfts, qxyz, Wstd,
                                                     Wf1, bf1, Wf2, bf2, ws, out, use_t);
}